// Round 5
// baseline (216.846 us; speedup 1.0000x reference)
//
#include <hip/hip_runtime.h>

#define N_ 1024
#define S_ 8
#define I_ 128
#define F_ 1024
#define M_ 512

typedef unsigned short ushort_t;
typedef __attribute__((ext_vector_type(8))) short bf16x8;
typedef __attribute__((ext_vector_type(8))) unsigned short u16x8;
typedef __attribute__((ext_vector_type(4))) float f32x4;

__device__ __forceinline__ unsigned short f2bf(float x) {
    unsigned int u = __float_as_uint(x);
    u += 0x7fffu + ((u >> 16) & 1u);   // round-to-nearest-even
    return (unsigned short)(u >> 16);
}

__device__ __forceinline__ float sigmoidf_(float x) {
    return 1.f / (1.f + __expf(-x));
}
__device__ __forceinline__ float tanhf_(float x) {
    float xc = fminf(fmaxf(x, -15.f), 15.f);
    float e = __expf(2.f * xc);
    return (e - 1.f) / (e + 1.f);
}

__device__ __forceinline__ void gload_lds16(const ushort_t* g, ushort_t* l) {
    __builtin_amdgcn_global_load_lds((const __attribute__((address_space(1))) void*)g,
                                     (__attribute__((address_space(3))) void*)l, 16, 0, 0);
}

// load 8 consecutive fp32, convert RNE->bf16, store 16B to LDS (16B-aligned)
__device__ __forceinline__ void cvt_store8(const float* __restrict__ gp, ushort_t* lp) {
    float4 a = ((const float4*)gp)[0];
    float4 b = ((const float4*)gp)[1];
    u16x8 v;
    v[0] = f2bf(a.x); v[1] = f2bf(a.y); v[2] = f2bf(a.z); v[3] = f2bf(a.w);
    v[4] = f2bf(b.x); v[5] = f2bf(b.y); v[6] = f2bf(b.z); v[7] = f2bf(b.w);
    *(u16x8*)lp = v;
}

// ---- fused 3-gate GEMM + LSTM elementwise -> h (bf16) ----
// fp32 inputs converted to bf16 inline during LDS staging (no separate convert pass).
// Block tile: 128 (n) x 64 (f), BK=64, padded LDS stride 72 elems.
// s-major XCD grouping: xcd = Lb&7 = s; per-XCD working set (~2 MB fp32) fits L2.
__global__ __launch_bounds__(256, 2) void k_gates(
    const float* __restrict__ x, const float* __restrict__ wxi,
    const float* __restrict__ wxg, const float* __restrict__ wxo,
    const float* __restrict__ bi, const float* __restrict__ bg,
    const float* __restrict__ bo, ushort_t* __restrict__ hb) {
    const int Lb   = blockIdx.x + 16 * blockIdx.y + 128 * blockIdx.z;
    const int s    = Lb & 7;             // stream == XCD
    const int slot = Lb >> 3;            // 0..127
    const int n0   = (slot & 7) * 128;
    const int f0   = (slot >> 3) * 64;
    // padded: 9 chunks (of 8 elems) per row; chunk 8 is pad (never written/read)
    __shared__ ushort_t sA[128 * 72];
    __shared__ ushort_t sB[3][64 * 72];
    const int tid  = threadIdx.x;
    const int lane = tid & 63;
    const int cl   = lane & 15;
    const int quad = lane >> 4;
    const int w    = tid >> 6;
    const int wm   = (w >> 1) * 64;  // wave row offset (n)
    const int wn   = (w & 1) * 32;   // wave col offset (f)

    f32x4 acc[3][4][2];
    #pragma unroll
    for (int g = 0; g < 3; ++g)
        #pragma unroll
        for (int mt = 0; mt < 4; ++mt)
            #pragma unroll
            for (int nt = 0; nt < 2; ++nt)
                acc[g][mt][nt] = (f32x4){0.f, 0.f, 0.f, 0.f};

    const float* wb0 = wxi + (size_t)s * (F_ * I_);
    const float* wb1 = wxg + (size_t)s * (F_ * I_);
    const float* wb2 = wxo + (size_t)s * (F_ * I_);

    for (int k0 = 0; k0 < 128; k0 += 64) {
        // stage A: 128 rows x 8 chunks = 1024 chunks, 4 per thread, fp32->bf16
        #pragma unroll
        for (int i = 0; i < 4; ++i) {
            int c = tid + i * 256;          // 0..1023
            int row = c >> 3, kc = c & 7;
            cvt_store8(x + (size_t)(n0 + row) * (S_ * I_) + s * I_ + k0 + kc * 8,
                       sA + row * 72 + kc * 8);
        }
        // stage B (3 gates): 64 x 8 = 512 chunks each, 2 per thread, fp32->bf16
        #pragma unroll
        for (int i = 0; i < 2; ++i) {
            int c = tid + i * 256;          // 0..511
            int row = c >> 3, kc = c & 7;
            size_t goff = (size_t)(f0 + row) * I_ + k0 + kc * 8;
            ushort_t* loff0 = &sB[0][row * 72 + kc * 8];
            cvt_store8(wb0 + goff, loff0);
            cvt_store8(wb1 + goff, &sB[1][row * 72 + kc * 8]);
            cvt_store8(wb2 + goff, &sB[2][row * 72 + kc * 8]);
        }
        __syncthreads();
        #pragma unroll
        for (int kk = 0; kk < 2; ++kk) {
            const int kb = kk * 32 + quad * 8;
            bf16x8 a[4];
            #pragma unroll
            for (int mt = 0; mt < 4; ++mt)
                a[mt] = *(const bf16x8*)(sA + (wm + mt * 16 + cl) * 72 + kb);
            #pragma unroll
            for (int g = 0; g < 3; ++g) {
                #pragma unroll
                for (int nt = 0; nt < 2; ++nt) {
                    bf16x8 b = *(const bf16x8*)(&sB[g][(wn + nt * 16 + cl) * 72 + kb]);
                    #pragma unroll
                    for (int mt = 0; mt < 4; ++mt)
                        acc[g][mt][nt] = __builtin_amdgcn_mfma_f32_16x16x32_bf16(
                            a[mt], b, acc[g][mt][nt], 0, 0, 0);
                }
            }
        }
        __syncthreads();
    }

    // epilogue: i=sig, g=tanh, o=sig; c=i*g; h=o*tanh(c)
    #pragma unroll
    for (int nt = 0; nt < 2; ++nt) {
        int fc = f0 + wn + nt * 16 + cl;
        float bii = bi[s * F_ + fc], bgg = bg[s * F_ + fc], boo = bo[s * F_ + fc];
        #pragma unroll
        for (int mt = 0; mt < 4; ++mt) {
            #pragma unroll
            for (int r = 0; r < 4; ++r) {
                int nr = n0 + wm + mt * 16 + quad * 4 + r;
                float pi = acc[0][mt][nt][r] + bii;
                float pg = acc[1][mt][nt][r] + bgg;
                float po = acc[2][mt][nt][r] + boo;
                float hv = sigmoidf_(po) * tanhf_(sigmoidf_(pi) * tanhf_(pg));
                hb[(size_t)s * (N_ * F_) + (size_t)nr * F_ + fc] = f2bf(hv);
            }
        }
    }
}

// ---- out GEMM: out[n, s*M+m] = sum_f h[s,n,f]*Wout[s,m,f] + bout[s,m] ----
// A (h, bf16) staged via global_load_lds DMA; B (Wout, fp32) converted inline.
// Block tile: 128 (n) x 64 (m), BK=128, padded LDS stride 136 elems.
// s-major XCD grouping: xcd = Lb&7 = s.
__global__ __launch_bounds__(256, 2) void k_out(
    const ushort_t* __restrict__ hb, const float* __restrict__ wout,
    const float* __restrict__ bout, float* __restrict__ out) {
    const int Lb   = blockIdx.x + 8 * blockIdx.y + 64 * blockIdx.z;
    const int s    = Lb & 7;            // stream == XCD
    const int slot = Lb >> 3;           // 0..63
    const int n0   = (slot & 7) * 128;
    const int m0   = (slot >> 3) * 64;
    // padded: 17 chunks per row; chunk 16 is pad
    __shared__ ushort_t sA[128 * 136];
    __shared__ ushort_t sB[64 * 136];
    const int tid  = threadIdx.x;
    const int lane = tid & 63;
    const int cl   = lane & 15;
    const int quad = lane >> 4;
    const int w    = tid >> 6;
    const int wm   = (w >> 1) * 64;
    const int wn   = (w & 1) * 32;

    f32x4 acc[4][2];
    #pragma unroll
    for (int mt = 0; mt < 4; ++mt)
        #pragma unroll
        for (int nt = 0; nt < 2; ++nt)
            acc[mt][nt] = (f32x4){0.f, 0.f, 0.f, 0.f};

    const ushort_t* ha = hb + (size_t)s * (N_ * F_);
    const float*    wa = wout + (size_t)s * (M_ * F_);

    for (int k0 = 0; k0 < 1024; k0 += 128) {
        // stage A (bf16 DMA): 128 x 17 = 2176 chunks (2176%64==0 -> wave-uniform guard)
        #pragma unroll
        for (int i = 0; i < 9; ++i) {
            unsigned c = (unsigned)tid + i * 256u;
            if (c < 2176u) {
                unsigned row = c / 17u, kc = c % 17u;
                unsigned kce = kc < 16u ? kc : 15u;
                gload_lds16(ha + (size_t)(n0 + row) * F_ + k0 + kce * 8, sA + c * 8);
            }
        }
        // stage B (fp32->bf16): 64 rows x 16 chunks = 1024, 4 per thread
        #pragma unroll
        for (int i = 0; i < 4; ++i) {
            int c = tid + i * 256;          // 0..1023
            int row = c >> 4, kc = c & 15;
            cvt_store8(wa + (size_t)(m0 + row) * F_ + k0 + kc * 8,
                       sB + row * 136 + kc * 8);
        }
        __syncthreads();
        #pragma unroll
        for (int kk = 0; kk < 4; ++kk) {
            const int kb = kk * 32 + quad * 8;
            bf16x8 a[4], b[2];
            #pragma unroll
            for (int mt = 0; mt < 4; ++mt)
                a[mt] = *(const bf16x8*)(sA + (wm + mt * 16 + cl) * 136 + kb);
            #pragma unroll
            for (int nt = 0; nt < 2; ++nt)
                b[nt] = *(const bf16x8*)(sB + (wn + nt * 16 + cl) * 136 + kb);
            #pragma unroll
            for (int nt = 0; nt < 2; ++nt)
                #pragma unroll
                for (int mt = 0; mt < 4; ++mt)
                    acc[mt][nt] = __builtin_amdgcn_mfma_f32_16x16x32_bf16(
                        a[mt], b[nt], acc[mt][nt], 0, 0, 0);
        }
        __syncthreads();
    }

    #pragma unroll
    for (int nt = 0; nt < 2; ++nt) {
        int mc = m0 + wn + nt * 16 + cl;
        float bb = bout[s * M_ + mc];
        #pragma unroll
        for (int mt = 0; mt < 4; ++mt) {
            #pragma unroll
            for (int r = 0; r < 4; ++r) {
                int nr = n0 + wm + mt * 16 + quad * 4 + r;
                out[(size_t)nr * (S_ * M_) + s * M_ + mc] = acc[mt][nt][r] + bb;
            }
        }
    }
}

extern "C" void kernel_launch(void* const* d_in, const int* in_sizes, int n_in,
                              void* d_out, int out_size, void* d_ws, size_t ws_size,
                              hipStream_t stream) {
    const float* mod  = (const float*)d_in[0];
    const float* Wxi  = (const float*)d_in[1];
    const float* bi   = (const float*)d_in[3];
    const float* Wxg  = (const float*)d_in[7];
    const float* bg   = (const float*)d_in[9];
    const float* Wxo  = (const float*)d_in[10];
    const float* bo   = (const float*)d_in[12];
    const float* Wout = (const float*)d_in[13];
    const float* bout = (const float*)d_in[14];

    ushort_t* hb = (ushort_t*)d_ws;   // h buffer: S*N*F bf16 = 16 MB

    k_gates<<<dim3(16, 8, 8), 256, 0, stream>>>(mod, Wxi, Wxg, Wxo, bi, bg, bo, hb);
    k_out<<<dim3(8, 8, 8), 256, 0, stream>>>(hb, Wout, bout, (float*)d_out);
}

// Round 6
// 215.954 us; speedup vs baseline: 1.0041x; 1.0041x over previous
//
#include <hip/hip_runtime.h>

#define N_ 1024
#define S_ 8
#define I_ 128
#define F_ 1024
#define M_ 512

typedef unsigned short ushort_t;
typedef __attribute__((ext_vector_type(8))) short bf16x8;
typedef __attribute__((ext_vector_type(8))) unsigned short u16x8;
typedef __attribute__((ext_vector_type(4))) float f32x4;

__device__ __forceinline__ unsigned short f2bf(float x) {
    unsigned int u = __float_as_uint(x);
    u += 0x7fffu + ((u >> 16) & 1u);   // round-to-nearest-even
    return (unsigned short)(u >> 16);
}

__device__ __forceinline__ float sigmoidf_(float x) {
    return 1.f / (1.f + __expf(-x));
}
__device__ __forceinline__ float tanhf_(float x) {
    float xc = fminf(fmaxf(x, -15.f), 15.f);
    float e = __expf(2.f * xc);
    return (e - 1.f) / (e + 1.f);
}

__device__ __forceinline__ void gload_lds16(const ushort_t* g, ushort_t* l) {
    __builtin_amdgcn_global_load_lds((const __attribute__((address_space(1))) void*)g,
                                     (__attribute__((address_space(3))) void*)l, 16, 0, 0);
}

// load 8 consecutive fp32, convert RNE->bf16, store 16B to LDS (16B-aligned)
__device__ __forceinline__ void cvt_store8(const float* __restrict__ gp, ushort_t* lp) {
    float4 a = ((const float4*)gp)[0];
    float4 b = ((const float4*)gp)[1];
    u16x8 v;
    v[0] = f2bf(a.x); v[1] = f2bf(a.y); v[2] = f2bf(a.z); v[3] = f2bf(a.w);
    v[4] = f2bf(b.x); v[5] = f2bf(b.y); v[6] = f2bf(b.z); v[7] = f2bf(b.w);
    *(u16x8*)lp = v;
}

// ---- fp32 -> bf16 conversion of modulation, Wxi, Wxg, Wxo into ws ----
// (Wout is converted inline in k_out; heavy staging operands stay on the DMA path.)
// ws layout (bf16 elems): xb@0 (1M), wib@1M, wgb@2M, wob@3M, hb@4M (8M)
__global__ __launch_bounds__(256) void k_convert(
    const float* __restrict__ mod, const float* __restrict__ wxi,
    const float* __restrict__ wxg, const float* __restrict__ wxo,
    ushort_t* __restrict__ ws) {
    unsigned v = blockIdx.x * 256u + threadIdx.x;  // float4 index, 0..1048575
    const float4* src; unsigned idx; ushort_t* dst;
    if (v < 262144u)       { src = (const float4*)mod;  idx = v;            dst = ws; }
    else if (v < 524288u)  { src = (const float4*)wxi;  idx = v - 262144u;  dst = ws + 1048576; }
    else if (v < 786432u)  { src = (const float4*)wxg;  idx = v - 524288u;  dst = ws + 2097152; }
    else                   { src = (const float4*)wxo;  idx = v - 786432u;  dst = ws + 3145728; }
    float4 f = src[idx];
    ushort4 o;
    o.x = f2bf(f.x); o.y = f2bf(f.y); o.z = f2bf(f.z); o.w = f2bf(f.w);
    ((ushort4*)dst)[idx] = o;
}

// ---- fused 3-gate GEMM + LSTM elementwise -> h (bf16) ----
// Block tile: 128 (n) x 64 (f), BK=64, padded LDS stride 72 elems.
// s-major XCD grouping: xcd = Lb&7 = s. All 128 blocks of stream s land on one
// XCD; its working set (~1 MB bf16) fits the 4 MB XCD L2.
__global__ __launch_bounds__(256, 2) void k_gates(
    const ushort_t* __restrict__ xb, const ushort_t* __restrict__ wib,
    const ushort_t* __restrict__ wgb, const ushort_t* __restrict__ wob,
    const float* __restrict__ bi, const float* __restrict__ bg,
    const float* __restrict__ bo, ushort_t* __restrict__ hb) {
    const int Lb   = blockIdx.x + 16 * blockIdx.y + 128 * blockIdx.z;
    const int s    = Lb & 7;             // stream == XCD
    const int slot = Lb >> 3;            // 0..127
    const int n0   = (slot & 7) * 128;
    const int f0   = (slot >> 3) * 64;
    // padded: 9 chunks (of 8 elems) per row; chunk 8 is pad (written, never read)
    __shared__ ushort_t sA[128 * 72];
    __shared__ ushort_t sB[3][64 * 72];
    const int tid  = threadIdx.x;
    const int lane = tid & 63;
    const int cl   = lane & 15;
    const int quad = lane >> 4;
    const int w    = tid >> 6;
    const int wm   = (w >> 1) * 64;  // wave row offset (n)
    const int wn   = (w & 1) * 32;   // wave col offset (f)

    f32x4 acc[3][4][2];
    #pragma unroll
    for (int g = 0; g < 3; ++g)
        #pragma unroll
        for (int mt = 0; mt < 4; ++mt)
            #pragma unroll
            for (int nt = 0; nt < 2; ++nt)
                acc[g][mt][nt] = (f32x4){0.f, 0.f, 0.f, 0.f};

    const ushort_t* wb0 = wib + (size_t)s * (F_ * I_);
    const ushort_t* wb1 = wgb + (size_t)s * (F_ * I_);
    const ushort_t* wb2 = wob + (size_t)s * (F_ * I_);

    for (int k0 = 0; k0 < 128; k0 += 64) {
        // stage A: 128 rows x 9 chunks = 1152 chunks (wave-uniform guard: 1152%64==0)
        #pragma unroll
        for (int i = 0; i < 5; ++i) {
            unsigned c = (unsigned)tid + i * 256u;
            if (c < 1152u) {
                unsigned row = c / 9u, kc = c % 9u;
                unsigned kce = kc < 8u ? kc : 7u;
                gload_lds16(xb + (size_t)(n0 + row) * (S_ * I_) + s * I_ + k0 + kce * 8,
                            sA + c * 8);
            }
        }
        // stage B (3 gates): 64 x 9 = 576 chunks each (576%64==0 -> wave-uniform)
        #pragma unroll
        for (int i = 0; i < 3; ++i) {
            unsigned c = (unsigned)tid + i * 256u;
            if (c < 576u) {
                unsigned row = c / 9u, kc = c % 9u;
                unsigned kce = kc < 8u ? kc : 7u;
                size_t goff = (size_t)(f0 + row) * I_ + k0 + kce * 8;
                gload_lds16(wb0 + goff, &sB[0][c * 8]);
                gload_lds16(wb1 + goff, &sB[1][c * 8]);
                gload_lds16(wb2 + goff, &sB[2][c * 8]);
            }
        }
        __syncthreads();
        #pragma unroll
        for (int kk = 0; kk < 2; ++kk) {
            const int kb = kk * 32 + quad * 8;
            bf16x8 a[4];
            #pragma unroll
            for (int mt = 0; mt < 4; ++mt)
                a[mt] = *(const bf16x8*)(sA + (wm + mt * 16 + cl) * 72 + kb);
            #pragma unroll
            for (int g = 0; g < 3; ++g) {
                #pragma unroll
                for (int nt = 0; nt < 2; ++nt) {
                    bf16x8 b = *(const bf16x8*)(&sB[g][(wn + nt * 16 + cl) * 72 + kb]);
                    #pragma unroll
                    for (int mt = 0; mt < 4; ++mt)
                        acc[g][mt][nt] = __builtin_amdgcn_mfma_f32_16x16x32_bf16(
                            a[mt], b, acc[g][mt][nt], 0, 0, 0);
                }
            }
        }
        __syncthreads();
    }

    // epilogue: i=sig, g=tanh, o=sig; c=i*g; h=o*tanh(c)
    #pragma unroll
    for (int nt = 0; nt < 2; ++nt) {
        int fc = f0 + wn + nt * 16 + cl;
        float bii = bi[s * F_ + fc], bgg = bg[s * F_ + fc], boo = bo[s * F_ + fc];
        #pragma unroll
        for (int mt = 0; mt < 4; ++mt) {
            #pragma unroll
            for (int r = 0; r < 4; ++r) {
                int nr = n0 + wm + mt * 16 + quad * 4 + r;
                float pi = acc[0][mt][nt][r] + bii;
                float pg = acc[1][mt][nt][r] + bgg;
                float po = acc[2][mt][nt][r] + boo;
                float hv = sigmoidf_(po) * tanhf_(sigmoidf_(pi) * tanhf_(pg));
                hb[(size_t)s * (N_ * F_) + (size_t)nr * F_ + fc] = f2bf(hv);
            }
        }
    }
}

// ---- out GEMM: out[n, s*M+m] = sum_f h[s,n,f]*Wout[s,m,f] + bout[s,m] ----
// A (h, bf16) staged via global_load_lds DMA; B (Wout, fp32) converted inline
// (light operand: 8 loads/thread/iter -- profiled OK in R5 while gates was not).
// Block tile: 128 (n) x 64 (m), BK=128, padded LDS stride 136 elems.
// s-major XCD grouping: xcd = Lb&7 = s.
__global__ __launch_bounds__(256, 2) void k_out(
    const ushort_t* __restrict__ hb, const float* __restrict__ wout,
    const float* __restrict__ bout, float* __restrict__ out) {
    const int Lb   = blockIdx.x + 8 * blockIdx.y + 64 * blockIdx.z;
    const int s    = Lb & 7;            // stream == XCD
    const int slot = Lb >> 3;           // 0..63
    const int n0   = (slot & 7) * 128;
    const int m0   = (slot >> 3) * 64;
    // padded: 17 chunks per row; chunk 16 is pad
    __shared__ ushort_t sA[128 * 136];
    __shared__ ushort_t sB[64 * 136];
    const int tid  = threadIdx.x;
    const int lane = tid & 63;
    const int cl   = lane & 15;
    const int quad = lane >> 4;
    const int w    = tid >> 6;
    const int wm   = (w >> 1) * 64;
    const int wn   = (w & 1) * 32;

    f32x4 acc[4][2];
    #pragma unroll
    for (int mt = 0; mt < 4; ++mt)
        #pragma unroll
        for (int nt = 0; nt < 2; ++nt)
            acc[mt][nt] = (f32x4){0.f, 0.f, 0.f, 0.f};

    const ushort_t* ha = hb + (size_t)s * (N_ * F_);
    const float*    wa = wout + (size_t)s * (M_ * F_);

    for (int k0 = 0; k0 < 1024; k0 += 128) {
        // stage A (bf16 DMA): 128 x 17 = 2176 chunks (2176%64==0 -> wave-uniform guard)
        #pragma unroll
        for (int i = 0; i < 9; ++i) {
            unsigned c = (unsigned)tid + i * 256u;
            if (c < 2176u) {
                unsigned row = c / 17u, kc = c % 17u;
                unsigned kce = kc < 16u ? kc : 15u;
                gload_lds16(ha + (size_t)(n0 + row) * F_ + k0 + kce * 8, sA + c * 8);
            }
        }
        // stage B (fp32->bf16 inline): 64 rows x 16 chunks = 1024, 4 per thread
        #pragma unroll
        for (int i = 0; i < 4; ++i) {
            int c = tid + i * 256;          // 0..1023
            int row = c >> 4, kc = c & 15;
            cvt_store8(wa + (size_t)(m0 + row) * F_ + k0 + kc * 8,
                       sB + row * 136 + kc * 8);
        }
        __syncthreads();
        #pragma unroll
        for (int kk = 0; kk < 4; ++kk) {
            const int kb = kk * 32 + quad * 8;
            bf16x8 a[4], b[2];
            #pragma unroll
            for (int mt = 0; mt < 4; ++mt)
                a[mt] = *(const bf16x8*)(sA + (wm + mt * 16 + cl) * 136 + kb);
            #pragma unroll
            for (int nt = 0; nt < 2; ++nt)
                b[nt] = *(const bf16x8*)(sB + (wn + nt * 16 + cl) * 136 + kb);
            #pragma unroll
            for (int nt = 0; nt < 2; ++nt)
                #pragma unroll
                for (int mt = 0; mt < 4; ++mt)
                    acc[mt][nt] = __builtin_amdgcn_mfma_f32_16x16x32_bf16(
                        a[mt], b[nt], acc[mt][nt], 0, 0, 0);
        }
        __syncthreads();
    }

    #pragma unroll
    for (int nt = 0; nt < 2; ++nt) {
        int mc = m0 + wn + nt * 16 + cl;
        float bb = bout[s * M_ + mc];
        #pragma unroll
        for (int mt = 0; mt < 4; ++mt) {
            #pragma unroll
            for (int r = 0; r < 4; ++r) {
                int nr = n0 + wm + mt * 16 + quad * 4 + r;
                out[(size_t)nr * (S_ * M_) + s * M_ + mc] = acc[mt][nt][r] + bb;
            }
        }
    }
}

extern "C" void kernel_launch(void* const* d_in, const int* in_sizes, int n_in,
                              void* d_out, int out_size, void* d_ws, size_t ws_size,
                              hipStream_t stream) {
    const float* mod  = (const float*)d_in[0];
    const float* Wxi  = (const float*)d_in[1];
    const float* bi   = (const float*)d_in[3];
    const float* Wxg  = (const float*)d_in[7];
    const float* bg   = (const float*)d_in[9];
    const float* Wxo  = (const float*)d_in[10];
    const float* bo   = (const float*)d_in[12];
    const float* Wout = (const float*)d_in[13];
    const float* bout = (const float*)d_in[14];

    ushort_t* ws  = (ushort_t*)d_ws;
    ushort_t* xb  = ws;
    ushort_t* wib = ws + 1048576;
    ushort_t* wgb = ws + 2097152;
    ushort_t* wob = ws + 3145728;
    ushort_t* hb  = ws + 4194304;

    k_convert<<<4096, 256, 0, stream>>>(mod, Wxi, Wxg, Wxo, ws);
    k_gates<<<dim3(16, 8, 8), 256, 0, stream>>>(xb, wib, wgb, wob, bi, bg, bo, hb);
    k_out<<<dim3(8, 8, 8), 256, 0, stream>>>(hb, Wout, bout, (float*)d_out);
}

// Round 7
// 201.601 us; speedup vs baseline: 1.0756x; 1.0712x over previous
//
#include <hip/hip_runtime.h>

#define N_ 1024
#define S_ 8
#define I_ 128
#define F_ 1024
#define M_ 512

typedef unsigned short ushort_t;
typedef __attribute__((ext_vector_type(8))) short bf16x8;
typedef __attribute__((ext_vector_type(4))) float f32x4;

__device__ __forceinline__ unsigned short f2bf(float x) {
    unsigned int u = __float_as_uint(x);
    u += 0x7fffu + ((u >> 16) & 1u);   // round-to-nearest-even
    return (unsigned short)(u >> 16);
}

#define LOG2E_ 1.442695041f

// division-free: v_rcp_f32 + v_exp_f32 (no IEEE div sequences in the epilogue)
__device__ __forceinline__ float sigmoidf_(float x) {
    return __builtin_amdgcn_rcpf(1.f + __builtin_amdgcn_exp2f(-LOG2E_ * x));
}
__device__ __forceinline__ float tanhf_(float x) {
    float xc = fminf(fmaxf(x, -15.f), 15.f);
    float e = __builtin_amdgcn_exp2f(2.f * LOG2E_ * xc);
    return (e - 1.f) * __builtin_amdgcn_rcpf(e + 1.f);
}

__device__ __forceinline__ void gload_lds16(const ushort_t* g, ushort_t* l) {
    __builtin_amdgcn_global_load_lds((const __attribute__((address_space(1))) void*)g,
                                     (__attribute__((address_space(3))) void*)l, 16, 0, 0);
}

// ---- fp32 -> bf16 conversion of modulation, Wxi, Wxg, Wxo, Wout into ws ----
// ws layout (bf16 elems): xb@0 (1M), wib@1M, wgb@2M, wob@3M, woutb@4M (4M), hb@8M (8M)
__global__ __launch_bounds__(256) void k_convert(
    const float* __restrict__ mod, const float* __restrict__ wxi,
    const float* __restrict__ wxg, const float* __restrict__ wxo,
    const float* __restrict__ wout, ushort_t* __restrict__ ws) {
    unsigned v = blockIdx.x * 256u + threadIdx.x;  // float4 index, 0..2097151
    const float4* src; unsigned idx; ushort_t* dst;
    if (v < 262144u)       { src = (const float4*)mod;  idx = v;            dst = ws; }
    else if (v < 524288u)  { src = (const float4*)wxi;  idx = v - 262144u;  dst = ws + 1048576; }
    else if (v < 786432u)  { src = (const float4*)wxg;  idx = v - 524288u;  dst = ws + 2097152; }
    else if (v < 1048576u) { src = (const float4*)wxo;  idx = v - 786432u;  dst = ws + 3145728; }
    else                   { src = (const float4*)wout; idx = v - 1048576u; dst = ws + 4194304; }
    float4 f = src[idx];
    ushort4 o;
    o.x = f2bf(f.x); o.y = f2bf(f.y); o.z = f2bf(f.z); o.w = f2bf(f.w);
    ((ushort4*)dst)[idx] = o;
}

// ---- fused 3-gate GEMM + LSTM elementwise -> h (bf16) ----
// Block tile: 128 (n) x 64 (f), BK=64, padded LDS stride 72 elems.
// s-major XCD grouping: xcd = Lb&7 = s. All 128 blocks of stream s land on one
// XCD; its working set (~1 MB bf16) fits the 4 MB XCD L2.
__global__ __launch_bounds__(256, 2) void k_gates(
    const ushort_t* __restrict__ xb, const ushort_t* __restrict__ wib,
    const ushort_t* __restrict__ wgb, const ushort_t* __restrict__ wob,
    const float* __restrict__ bi, const float* __restrict__ bg,
    const float* __restrict__ bo, ushort_t* __restrict__ hb) {
    const int Lb   = blockIdx.x + 16 * blockIdx.y + 128 * blockIdx.z;
    const int s    = Lb & 7;             // stream == XCD
    const int slot = Lb >> 3;            // 0..127
    const int n0   = (slot & 7) * 128;
    const int f0   = (slot >> 3) * 64;
    // padded: 9 chunks (of 8 elems) per row; chunk 8 is pad (written, never read)
    __shared__ ushort_t sA[128 * 72];
    __shared__ ushort_t sB[3][64 * 72];
    const int tid  = threadIdx.x;
    const int lane = tid & 63;
    const int cl   = lane & 15;
    const int quad = lane >> 4;
    const int w    = tid >> 6;
    const int wm   = (w >> 1) * 64;  // wave row offset (n)
    const int wn   = (w & 1) * 32;   // wave col offset (f)

    f32x4 acc[3][4][2];
    #pragma unroll
    for (int g = 0; g < 3; ++g)
        #pragma unroll
        for (int mt = 0; mt < 4; ++mt)
            #pragma unroll
            for (int nt = 0; nt < 2; ++nt)
                acc[g][mt][nt] = (f32x4){0.f, 0.f, 0.f, 0.f};

    const ushort_t* wb0 = wib + (size_t)s * (F_ * I_);
    const ushort_t* wb1 = wgb + (size_t)s * (F_ * I_);
    const ushort_t* wb2 = wob + (size_t)s * (F_ * I_);

    for (int k0 = 0; k0 < 128; k0 += 64) {
        // stage A: 128 rows x 9 chunks = 1152 chunks (wave-uniform guard: 1152%64==0)
        #pragma unroll
        for (int i = 0; i < 5; ++i) {
            unsigned c = (unsigned)tid + i * 256u;
            if (c < 1152u) {
                unsigned row = c / 9u, kc = c % 9u;
                unsigned kce = kc < 8u ? kc : 7u;
                gload_lds16(xb + (size_t)(n0 + row) * (S_ * I_) + s * I_ + k0 + kce * 8,
                            sA + c * 8);
            }
        }
        // stage B (3 gates): 64 x 9 = 576 chunks each (576%64==0 -> wave-uniform)
        #pragma unroll
        for (int i = 0; i < 3; ++i) {
            unsigned c = (unsigned)tid + i * 256u;
            if (c < 576u) {
                unsigned row = c / 9u, kc = c % 9u;
                unsigned kce = kc < 8u ? kc : 7u;
                size_t goff = (size_t)(f0 + row) * I_ + k0 + kce * 8;
                gload_lds16(wb0 + goff, &sB[0][c * 8]);
                gload_lds16(wb1 + goff, &sB[1][c * 8]);
                gload_lds16(wb2 + goff, &sB[2][c * 8]);
            }
        }
        __syncthreads();
        #pragma unroll
        for (int kk = 0; kk < 2; ++kk) {
            const int kb = kk * 32 + quad * 8;
            bf16x8 a[4];
            #pragma unroll
            for (int mt = 0; mt < 4; ++mt)
                a[mt] = *(const bf16x8*)(sA + (wm + mt * 16 + cl) * 72 + kb);
            #pragma unroll
            for (int g = 0; g < 3; ++g) {
                #pragma unroll
                for (int nt = 0; nt < 2; ++nt) {
                    bf16x8 b = *(const bf16x8*)(&sB[g][(wn + nt * 16 + cl) * 72 + kb]);
                    #pragma unroll
                    for (int mt = 0; mt < 4; ++mt)
                        acc[g][mt][nt] = __builtin_amdgcn_mfma_f32_16x16x32_bf16(
                            a[mt], b, acc[g][mt][nt], 0, 0, 0);
                }
            }
        }
        __syncthreads();
    }

    // epilogue: i=sig, g=tanh, o=sig; c=i*g; h=o*tanh(c)  (division-free)
    #pragma unroll
    for (int nt = 0; nt < 2; ++nt) {
        int fc = f0 + wn + nt * 16 + cl;
        float bii = bi[s * F_ + fc], bgg = bg[s * F_ + fc], boo = bo[s * F_ + fc];
        #pragma unroll
        for (int mt = 0; mt < 4; ++mt) {
            #pragma unroll
            for (int r = 0; r < 4; ++r) {
                int nr = n0 + wm + mt * 16 + quad * 4 + r;
                float pi = acc[0][mt][nt][r] + bii;
                float pg = acc[1][mt][nt][r] + bgg;
                float po = acc[2][mt][nt][r] + boo;
                float hv = sigmoidf_(po) * tanhf_(sigmoidf_(pi) * tanhf_(pg));
                hb[(size_t)s * (N_ * F_) + (size_t)nr * F_ + fc] = f2bf(hv);
            }
        }
    }
}

// ---- out GEMM: out[n, s*M+m] = sum_f h[s,n,f]*Wout[s,m,f] + bout[s,m] ----
// Block tile: 128 (n) x 64 (m), BK=128, padded LDS stride 136 elems.
// s-major XCD grouping: xcd = Lb&7 = s. All 64 blocks of stream s on one XCD;
// working set h[s] (2 MB) + Wout[s] (1 MB) fits the 4 MB L2.
__global__ __launch_bounds__(256, 2) void k_out(
    const ushort_t* __restrict__ hb, const ushort_t* __restrict__ woutb,
    const float* __restrict__ bout, float* __restrict__ out) {
    const int Lb   = blockIdx.x + 8 * blockIdx.y + 64 * blockIdx.z;
    const int s    = Lb & 7;            // stream == XCD
    const int slot = Lb >> 3;           // 0..63
    const int n0   = (slot & 7) * 128;
    const int m0   = (slot >> 3) * 64;
    // padded: 17 chunks per row; chunk 16 is pad
    __shared__ ushort_t sA[128 * 136];
    __shared__ ushort_t sB[64 * 136];
    const int tid  = threadIdx.x;
    const int lane = tid & 63;
    const int cl   = lane & 15;
    const int quad = lane >> 4;
    const int w    = tid >> 6;
    const int wm   = (w >> 1) * 64;
    const int wn   = (w & 1) * 32;

    f32x4 acc[4][2];
    #pragma unroll
    for (int mt = 0; mt < 4; ++mt)
        #pragma unroll
        for (int nt = 0; nt < 2; ++nt)
            acc[mt][nt] = (f32x4){0.f, 0.f, 0.f, 0.f};

    const ushort_t* ha = hb + (size_t)s * (N_ * F_);
    const ushort_t* wa = woutb + (size_t)s * (M_ * F_);

    for (int k0 = 0; k0 < 1024; k0 += 128) {
        // stage A: 128 x 17 = 2176 chunks (2176%64==0 -> wave-uniform guard)
        #pragma unroll
        for (int i = 0; i < 9; ++i) {
            unsigned c = (unsigned)tid + i * 256u;
            if (c < 2176u) {
                unsigned row = c / 17u, kc = c % 17u;
                unsigned kce = kc < 16u ? kc : 15u;
                gload_lds16(ha + (size_t)(n0 + row) * F_ + k0 + kce * 8, sA + c * 8);
            }
        }
        // stage B: 64 x 17 = 1088 chunks (1088%64==0)
        #pragma unroll
        for (int i = 0; i < 5; ++i) {
            unsigned c = (unsigned)tid + i * 256u;
            if (c < 1088u) {
                unsigned row = c / 17u, kc = c % 17u;
                unsigned kce = kc < 16u ? kc : 15u;
                gload_lds16(wa + (size_t)(m0 + row) * F_ + k0 + kce * 8, sB + c * 8);
            }
        }
        __syncthreads();
        #pragma unroll
        for (int kk = 0; kk < 4; ++kk) {
            const int kb = kk * 32 + quad * 8;
            bf16x8 a[4], b[2];
            #pragma unroll
            for (int mt = 0; mt < 4; ++mt)
                a[mt] = *(const bf16x8*)(sA + (wm + mt * 16 + cl) * 136 + kb);
            #pragma unroll
            for (int nt = 0; nt < 2; ++nt)
                b[nt] = *(const bf16x8*)(sB + (wn + nt * 16 + cl) * 136 + kb);
            #pragma unroll
            for (int nt = 0; nt < 2; ++nt)
                #pragma unroll
                for (int mt = 0; mt < 4; ++mt)
                    acc[mt][nt] = __builtin_amdgcn_mfma_f32_16x16x32_bf16(
                        a[mt], b[nt], acc[mt][nt], 0, 0, 0);
        }
        __syncthreads();
    }

    #pragma unroll
    for (int nt = 0; nt < 2; ++nt) {
        int mc = m0 + wn + nt * 16 + cl;
        float bb = bout[s * M_ + mc];
        #pragma unroll
        for (int mt = 0; mt < 4; ++mt) {
            #pragma unroll
            for (int r = 0; r < 4; ++r) {
                int nr = n0 + wm + mt * 16 + quad * 4 + r;
                out[(size_t)nr * (S_ * M_) + s * M_ + mc] = acc[mt][nt][r] + bb;
            }
        }
    }
}

extern "C" void kernel_launch(void* const* d_in, const int* in_sizes, int n_in,
                              void* d_out, int out_size, void* d_ws, size_t ws_size,
                              hipStream_t stream) {
    const float* mod  = (const float*)d_in[0];
    const float* Wxi  = (const float*)d_in[1];
    const float* bi   = (const float*)d_in[3];
    const float* Wxg  = (const float*)d_in[7];
    const float* bg   = (const float*)d_in[9];
    const float* Wxo  = (const float*)d_in[10];
    const float* bo   = (const float*)d_in[12];
    const float* Wout = (const float*)d_in[13];
    const float* bout = (const float*)d_in[14];

    ushort_t* ws  = (ushort_t*)d_ws;
    ushort_t* xb  = ws;
    ushort_t* wib = ws + 1048576;
    ushort_t* wgb = ws + 2097152;
    ushort_t* wob = ws + 3145728;
    ushort_t* wtb = ws + 4194304;
    ushort_t* hb  = ws + 8388608;

    k_convert<<<8192, 256, 0, stream>>>(mod, Wxi, Wxg, Wxo, Wout, ws);
    k_gates<<<dim3(16, 8, 8), 256, 0, stream>>>(xb, wib, wgb, wob, bi, bg, bo, hb);
    k_out<<<dim3(8, 8, 8), 256, 0, stream>>>(hb, wtb, bout, (float*)d_out);
}